// Round 1
// baseline (1038.497 us; speedup 1.0000x reference)
//
#include <hip/hip_runtime.h>
#include <stdint.h>

#define NROWS 500000
#define NROWS4 125000
#define NCLS 100
#define NBINS 15
#define NSUB 64          // sub-bucket = 4096 ULP; ~70 elems/sub near mode -> rank err << tolerance
#define B1 14
#define CH1 8929         // ceil(125000/14) float4s per hist1 block
#define B2 16
#define CH2 7813         // ceil(125000/16) float4s per scan2 block
#define HSZ (NBINS * NSUB)   // 960

__device__ __forceinline__ int rank_target(int b) {
    if (b == 0) return 0;
    const float step = 500000.0f / 15.0f;   // float32-rounded, mimics jnp.linspace
    return (int)floorf((float)b * step);
}

// Pass 1: row softmax of logits [N][C], write transposed probsT [C][N].
// Also emits labConf[n] = prob of the labeled class (bit-identical product to
// the stored probsT value), so k_label never has to gather probsT.
__global__ __launch_bounds__(256) void k_softmax_t(const float* __restrict__ logits,
                                                   const int* __restrict__ labels,
                                                   float* __restrict__ probsT,
                                                   float* __restrict__ labConf) {
    __shared__ float tile[64][101];
    __shared__ float red[256];
    __shared__ float mx[64];
    __shared__ float inv[64];
    const int row0 = blockIdx.x * 64;
    const int rows = min(64, NROWS - row0);
    const int t = threadIdx.x;
    const int total = rows * NCLS;
    for (int k = t; k < total; k += 256) {
        int r = k / NCLS, c = k - r * NCLS;
        tile[r][c] = logits[(size_t)(row0 + r) * NCLS + c];
    }
    __syncthreads();
    const int r = t >> 2, q = t & 3;   // 4 threads per row
    if (r < rows) {
        float m = -1e30f;
        #pragma unroll
        for (int c = 0; c < 25; ++c) m = fmaxf(m, tile[r][q * 25 + c]);
        red[t] = m;
    }
    __syncthreads();
    if (r < rows && q == 0)
        mx[r] = fmaxf(fmaxf(red[t], red[t + 1]), fmaxf(red[t + 2], red[t + 3]));
    __syncthreads();
    if (r < rows) {
        float m = mx[r], s = 0.f;
        #pragma unroll
        for (int c = 0; c < 25; ++c) {
            float e = __expf(tile[r][q * 25 + c] - m);
            tile[r][q * 25 + c] = e;
            s += e;
        }
        red[t] = s;
    }
    __syncthreads();
    if (r < rows && q == 0)
        inv[r] = 1.0f / (red[t] + red[t + 1] + red[t + 2] + red[t + 3]);
    __syncthreads();
    if (t < rows) {
        const int lab = labels[row0 + t];
        labConf[row0 + t] = tile[t][lab] * inv[t];   // same product as probsT store
    }
    const int shift = (rows == 64) ? 4 : 3;
    const int gq = 1 << shift;
    const int ng = NCLS << shift;
    for (int k = t; k < ng; k += 256) {
        int c = k >> shift, g = k & (gq - 1);
        int rr = g << 2;
        float4 o;
        o.x = tile[rr + 0][c] * inv[rr + 0];
        o.y = tile[rr + 1][c] * inv[rr + 1];
        o.z = tile[rr + 2][c] * inv[rr + 2];
        o.w = tile[rr + 3][c] * inv[rr + 3];
        *(float4*)(probsT + (size_t)c * NROWS + row0 + rr) = o;
    }
}

// Pass 2: per-class L1 histogram (top 12 used float bits), 2 bank-rotated LDS
// copies, non-atomic flush to private copy per blockIdx.x
__global__ __launch_bounds__(256) void k_hist1(const float4* __restrict__ probsT4,
                                               int* __restrict__ hist1p) {
    __shared__ int h[2][4096];   // 32 KB
    const int c = blockIdx.y, t = threadIdx.x;
    int4* hz = (int4*)&h[0][0];
    for (int i = t; i < 2048; i += 256) hz[i] = make_int4(0, 0, 0, 0);
    __syncthreads();
    const int copy = t & 1;
    const int rot = copy << 4;
    const size_t base = (size_t)c * NROWS4;
    const int start = blockIdx.x * CH1;
    const int end = min(NROWS4, start + CH1);
    for (int i = start + t; i < end; i += 256) {
        float4 v = probsT4[base + i];
        atomicAdd(&h[copy][((__float_as_uint(v.x) >> 18) + rot) & 4095], 1);
        atomicAdd(&h[copy][((__float_as_uint(v.y) >> 18) + rot) & 4095], 1);
        atomicAdd(&h[copy][((__float_as_uint(v.z) >> 18) + rot) & 4095], 1);
        atomicAdd(&h[copy][((__float_as_uint(v.w) >> 18) + rot) & 4095], 1);
    }
    __syncthreads();
    int* out = hist1p + ((size_t)blockIdx.x * NCLS + c) * 4096;
    for (int i = t; i < 4096; i += 256)
        out[i] = h[0][i] + h[1][(i + 16) & 4095];
}

// Select L1 bucket per rank target; parallel prefix (shfl), dedupe via owner[]
// (owner = LAST slot of a duplicate-target group, matching scan2's upper_bound)
__global__ __launch_bounds__(256) void k_sel1(const int* __restrict__ hist1p,
                                              int* __restrict__ tgt,
                                              int* __restrict__ below,
                                              int* __restrict__ owner) {
    __shared__ int wsum[4];
    __shared__ int stgt[NBINS];
    __shared__ int sbelow[NBINS];
    const int c = blockIdx.x, t = threadIdx.x;
    int4 acc[4] = {make_int4(0,0,0,0), make_int4(0,0,0,0),
                   make_int4(0,0,0,0), make_int4(0,0,0,0)};
    for (int k = 0; k < B1; ++k) {
        const int4* p = (const int4*)(hist1p + ((size_t)k * NCLS + c) * 4096) + t * 4;
        #pragma unroll
        for (int j = 0; j < 4; ++j) {
            int4 v = p[j];
            acc[j].x += v.x; acc[j].y += v.y; acc[j].z += v.z; acc[j].w += v.w;
        }
    }
    int loc[16];
    #pragma unroll
    for (int j = 0; j < 4; ++j) {
        loc[j * 4 + 0] = acc[j].x; loc[j * 4 + 1] = acc[j].y;
        loc[j * 4 + 2] = acc[j].z; loc[j * 4 + 3] = acc[j].w;
    }
    int s = 0;
    #pragma unroll
    for (int i = 0; i < 16; ++i) s += loc[i];
    // block-wide exclusive prefix of per-thread totals
    const int lane = t & 63, w = t >> 6;
    int incl = s;
    #pragma unroll
    for (int d = 1; d < 64; d <<= 1) {
        int n = __shfl_up(incl, d, 64);
        if (lane >= d) incl += n;
    }
    if (lane == 63) wsum[w] = incl;
    __syncthreads();
    int woff = 0;
    #pragma unroll
    for (int j = 0; j < 4; ++j) if (j < w) woff += wsum[j];
    const int cum0 = woff + incl - s;
    for (int b = 0; b < NBINS; ++b) {
        const int f = rank_target(b);
        int cc = cum0;
        #pragma unroll
        for (int i = 0; i < 16; ++i) {
            if (f >= cc && f < cc + loc[i]) { stgt[b] = t * 16 + i; sbelow[b] = cc; }
            cc += loc[i];
        }
    }
    __syncthreads();
    if (t == 0) {
        int ow = NBINS - 1;
        for (int b = NBINS - 1; b >= 0; --b) {
            if (b == NBINS - 1 || stgt[b] != stgt[b + 1]) ow = b;   // last-of-group
            owner[c * NBINS + b] = ow;
            tgt[c * NBINS + b] = stgt[b];
            below[c * NBINS + b] = sbelow[b];
        }
    }
}

// Pass 3 (rewritten): one scan produces (a) per-target-bucket sub-hists
// {n, sum v, sum v^2} and (b) EQUAL-COUNT SEGMENT sums {T, Q} per segment
// j = #{b : stg[b] <= bucket(v)}  (16 segments).  A 4096-entry LDS byte table
// maps bucket -> {segment | target-flag}, replacing the per-bin min-trick
// (45 VALU/elem) with 1 LDS byte read + 2 LDS float atomics per element.
// Contention is bounded: segments are equal-count by construction (~2-way
// with the 2 rotated copies).  Block segment totals flush via global atomics
// into segG[c][16][2].
__global__ __launch_bounds__(256) void k_scan2(const float4* __restrict__ probsT4,
                                               const int* __restrict__ tgt,
                                               int* __restrict__ scan2p,
                                               float* __restrict__ segG) {
    __shared__ int stg[16];
    __shared__ unsigned char tbl[4096];
    __shared__ float segT[2][16];
    __shared__ float segQ[2][16];
    __shared__ int hn[HSZ];
    __shared__ float hT[HSZ];
    __shared__ float hQ[HSZ];
    const int c = blockIdx.y, t = threadIdx.x;
    if (t < 16) stg[t] = (t < NBINS) ? tgt[c * NBINS + t] : 0x7FFFFFFF;
    if (t < 32) { segT[t >> 4][t & 15] = 0.f; segQ[t >> 4][t & 15] = 0.f; }
    for (int i = t; i < HSZ; i += 256) { hn[i] = 0; hT[i] = 0.f; hQ[i] = 0.f; }
    __syncthreads();                      // stg ready
    // build bucket->segment table: thread t owns buckets [t*16, t*16+16)
    {
        const int k0 = t * 16;
        int j = 0;                        // j(k0) = #{stg <= k0}, 4-step upper search
        j += (stg[j + 7] <= k0) ? 8 : 0;
        j += (stg[j + 3] <= k0) ? 4 : 0;
        j += (stg[j + 1] <= k0) ? 2 : 0;
        j += (stg[j] <= k0) ? 1 : 0;
        for (int k = k0; k < k0 + 16; ++k) {
            while (j < NBINS && stg[j] <= k) ++j;
            tbl[k] = (unsigned char)j;
        }
    }
    __syncthreads();                      // j-values filled
    if (t < NBINS) tbl[stg[t]] |= 0x80;   // flag target buckets (dupes idempotent)
    __syncthreads();
    const size_t base = (size_t)c * NROWS4;
    const int start = blockIdx.x * CH2;
    const int end = min(NROWS4, start + CH2);
    const int cp = t & 1;
    for (int i = start + t; i < end; i += 256) {
        float4 v = probsT4[base + i];
        float val[4] = {v.x, v.y, v.z, v.w};
        unsigned bx[4] = {__float_as_uint(v.x), __float_as_uint(v.y),
                          __float_as_uint(v.z), __float_as_uint(v.w)};
        #pragma unroll
        for (int e = 0; e < 4; ++e) {
            const int k1 = (int)(bx[e] >> 18);
            const unsigned b8 = (unsigned)tbl[k1];
            const int j = (int)(b8 & 15u);
            atomicAdd(&segT[cp][j], val[e]);
            atomicAdd(&segQ[cp][j], val[e] * val[e]);
            if (b8 & 0x80u) {             // inside a target bucket: sub-histogram
                int sub = (j - 1) * NSUB + (int)((bx[e] >> 12) & (NSUB - 1));
                atomicAdd(&hn[sub], 1);
                atomicAdd(&hT[sub], val[e]);
                atomicAdd(&hQ[sub], val[e] * val[e]);
            }
        }
    }
    __syncthreads();
    // flush private sub-hist copy: [blk*NCLS+c][3][960]
    int* on = scan2p + ((size_t)(blockIdx.x * NCLS + c) * 3) * HSZ;
    float* oT = (float*)(on + HSZ);
    float* oQ = (float*)(on + 2 * HSZ);
    for (int i = t; i < HSZ; i += 256) { on[i] = hn[i]; oT[i] = hT[i]; oQ[i] = hQ[i]; }
    // flush block segment totals
    if (t < 16) {
        float T = segT[0][t] + segT[1][t];
        float Q = segQ[0][t] + segQ[1][t];
        atomicAdd(&segG[c * 32 + 2 * t], T);
        atomicAdd(&segG[c * 32 + 2 * t + 1], Q);
    }
}

// Select sub-bucket (single wave, shfl prefix over 64 subs); cumulative {N,T,Q}
// at the boundary: cumT[b] = sum_{j<=b} segT[j] + sub-prefix (assembled in double)
__global__ __launch_bounds__(64) void k_sel2(const int* __restrict__ scan2p,
                                             const int* __restrict__ tgt,
                                             const int* __restrict__ below,
                                             const int* __restrict__ owner,
                                             const float* __restrict__ segG,
                                             float* __restrict__ bounds,
                                             int* __restrict__ cumN,
                                             double* __restrict__ cumT,
                                             double* __restrict__ cumQ) {
    const int b = blockIdx.x, c = blockIdx.y, t = threadIdx.x;   // t < 64
    const int ow = owner[c * NBINS + b];
    int nj = 0; float Tj = 0.f, Qj = 0.f;
    for (int k = 0; k < B2; ++k) {
        const int* p = scan2p + ((size_t)(k * NCLS + c) * 3) * HSZ + ow * NSUB + t;
        nj += p[0];
        Tj += ((const float*)p)[HSZ];
        Qj += ((const float*)p)[2 * HSZ];
    }
    const int own = nj;
    #pragma unroll
    for (int d = 1; d < 64; d <<= 1) {
        int nn = __shfl_up(nj, d, 64);
        float TT = __shfl_up(Tj, d, 64);
        float QQ = __shfl_up(Qj, d, 64);
        if (t >= d) { nj += nn; Tj += TT; Qj += QQ; }
    }
    const int bel = below[c * NBINS + b];
    const int lr = rank_target(b) - bel;
    if (lr >= nj - own && lr < nj) {
        unsigned bits = ((unsigned)tgt[c * NBINS + b] << 18) | ((unsigned)t << 12) | 0xFFFu;
        bounds[c * NBINS + b] = __uint_as_float(bits);
        cumN[c * NBINS + b] = bel + nj;
        double A = 0.0, Qd = 0.0;
        for (int j = 0; j <= b; ++j) {
            A  += (double)segG[c * 32 + 2 * j];
            Qd += (double)segG[c * 32 + 2 * j + 1];
        }
        cumT[c * NBINS + b] = A + (double)Tj;
        cumQ[c * NBINS + b] = Qd + (double)Qj;
    }
}

// Pass 4: label correction from the compact labConf array (coalesced), LDS-staged
// bounds table + LDS-staged accumulator, one filtered global-atomic flush per block
__global__ __launch_bounds__(256) void k_label(const float* __restrict__ labConf,
                                               const int* __restrict__ labels,
                                               const float* __restrict__ bounds,
                                               float* __restrict__ accLab) {
    __shared__ float sbd[NCLS * NBINS];        // 6 KB
    __shared__ float sacc[NCLS * NBINS * 2];   // 12 KB
    const int t = threadIdx.x;
    for (int i = t; i < NCLS * NBINS; i += 256) sbd[i] = bounds[i];
    for (int i = t; i < NCLS * NBINS * 2; i += 256) sacc[i] = 0.f;
    __syncthreads();
    for (int n = blockIdx.x * 256 + t; n < NROWS; n += gridDim.x * 256) {
        const int c = labels[n];
        const float conf = labConf[n];
        const float* bd = sbd + c * NBINS;
        if (conf > bd[0]) {
            int idx = 0;
            #pragma unroll
            for (int b = 1; b < NBINS; ++b) idx += (conf > bd[b]) ? 1 : 0;
            atomicAdd(&sacc[(c * NBINS + idx) * 2 + 0], 1.0f);
            atomicAdd(&sacc[(c * NBINS + idx) * 2 + 1], conf);
        }
    }
    __syncthreads();
    for (int i = t; i < NCLS * NBINS * 2; i += 256)
        if (sacc[i] != 0.f) atomicAdd(&accLab[i], sacc[i]);
}

// Pass 5: closed-form LOO combine in double (totals from segment sums)
__global__ __launch_bounds__(256) void k_final(const float* __restrict__ segG,
                                               const int* __restrict__ cumN,
                                               const double* __restrict__ cumT,
                                               const double* __restrict__ cumQ,
                                               const float* __restrict__ accLab,
                                               float* __restrict__ out) {
    __shared__ double red[256];
    const int t = threadIdx.x;
    double local = 0.0;
    for (int k = t; k < NCLS * NBINS; k += 256) {
        int c = k / NBINS, b = k - c * NBINS;
        double n, T, Q;
        if (b < NBINS - 1) {
            n = (double)(cumN[k + 1] - cumN[k]);
            T = cumT[k + 1] - cumT[k];
            Q = cumQ[k + 1] - cumQ[k];
        } else {
            double sT = 0.0, sQ = 0.0;
            for (int j = 0; j < 16; ++j) {
                sT += (double)segG[c * 32 + 2 * j];
                sQ += (double)segG[c * 32 + 2 * j + 1];
            }
            n = (double)(NROWS - cumN[k]);
            T = sT - cumT[k];
            Q = sQ - cumQ[k];
        }
        double S = accLab[k * 2 + 0], T1 = accLab[k * 2 + 1];
        if (n > 1.5) {
            double inv = 1.0 / (n - 1.0);
            double a0 = S * inv, a1 = (S - 1.0) * inv;
            local += Q - 2.0 * a0 * T + 2.0 * T1 * inv + (n - S) * a0 * a0 + S * a1 * a1;
        }
    }
    red[t] = local;
    __syncthreads();
    for (int s = 128; s; s >>= 1) {
        if (t < s) red[t] += red[t + s];
        __syncthreads();
    }
    if (t == 0) out[0] = (float)(red[0] / ((double)NROWS * (double)NCLS));
}

extern "C" void kernel_launch(void* const* d_in, const int* in_sizes, int n_in,
                              void* d_out, int out_size, void* d_ws, size_t ws_size,
                              hipStream_t stream) {
    const float* logits = (const float*)d_in[0];
    const int* labels = (const int*)d_in[1];
    float* out = (float*)d_out;
    char* ws = (char*)d_ws;
    size_t off = 0;
    auto alloc = [&](size_t bytes) -> void* {
        off = (off + 255) & ~(size_t)255;
        void* p = ws + off;
        off += bytes;
        return p;
    };
    float* probsT = (float*)alloc((size_t)NCLS * NROWS * 4);               // 200 MB
    // shared region: hist1p (hist1->sel1) then reused as scan2p (scan2->sel2)
    size_t h1bytes = (size_t)B1 * NCLS * 4096 * 4;                         // 22.9 MB
    size_t s2bytes = (size_t)B2 * NCLS * 3 * HSZ * 4;                      // 18.4 MB
    int* hist1p = (int*)alloc(h1bytes > s2bytes ? h1bytes : s2bytes);
    int* scan2p = hist1p;
    float* labConf = (float*)alloc((size_t)NROWS * 4);                     // 2 MB
    // --- zeroed region (contiguous, single small memset) ---
    char* zbase = ws + ((off + 255) & ~(size_t)255);
    float* segG   = (float*)alloc((size_t)NCLS * 32 * 4);                  // [c][16]{T,Q}
    float* accLab = (float*)alloc((size_t)NCLS * NBINS * 2 * 4);
    size_t zlen = (size_t)((ws + off) - zbase);
    // --- written-before-read region ---
    int*    tgt     = (int*)alloc((size_t)NCLS * NBINS * 4);
    int*    below   = (int*)alloc((size_t)NCLS * NBINS * 4);
    int*    owner   = (int*)alloc((size_t)NCLS * NBINS * 4);
    float*  bounds  = (float*)alloc((size_t)NCLS * NBINS * 4);
    int*    cumN    = (int*)alloc((size_t)NCLS * NBINS * 4);
    double* cumT    = (double*)alloc((size_t)NCLS * NBINS * 8);
    double* cumQ    = (double*)alloc((size_t)NCLS * NBINS * 8);
    if (off > ws_size) {
        hipMemsetAsync(d_out, 0xFF, 4, stream);   // NaN sentinel
        return;
    }
    hipMemsetAsync(zbase, 0, zlen, stream);

    k_softmax_t<<<(NROWS + 63) / 64, 256, 0, stream>>>(logits, labels, probsT, labConf);
    k_hist1<<<dim3(B1, NCLS), 256, 0, stream>>>((const float4*)probsT, hist1p);
    k_sel1<<<NCLS, 256, 0, stream>>>(hist1p, tgt, below, owner);
    k_scan2<<<dim3(B2, NCLS), 256, 0, stream>>>((const float4*)probsT, tgt, scan2p, segG);
    k_sel2<<<dim3(NBINS, NCLS), 64, 0, stream>>>(scan2p, tgt, below, owner, segG,
                                                 bounds, cumN, cumT, cumQ);
    k_label<<<128, 256, 0, stream>>>(labConf, labels, bounds, accLab);
    k_final<<<1, 256, 0, stream>>>(segG, cumN, cumT, cumQ, accLab, out);
}